// Round 9
// baseline (345.695 us; speedup 1.0000x reference)
//
#include <hip/hip_runtime.h>
#include <math.h>

#define VOCAB 32000
#define E_DIM 512
#define H_DIM 1024
#define S_LEN 50
#define B_SZ 64
#define T_LEN 10
#define H3 (3 * H_DIM)
#define D2H (2 * H_DIM)

#define NBLK 256
#define NGRU 64
#define NGEMM 192
#define WS_STRIDE 1032   // LDS row stride (2064B): 2-way max bank alias = free

typedef __attribute__((ext_vector_type(8))) short short8;
typedef __attribute__((ext_vector_type(4))) float floatx4;

__device__ __forceinline__ ushort f2b(float f) {
    union { float f; uint32_t u; } x; x.f = f;
    uint32_t r = (x.u + 0x7fff + ((x.u >> 16) & 1)) >> 16;  // RNE
    return (ushort)r;
}
__device__ __forceinline__ float b2f(ushort u) {
    union { float f; uint32_t u; } x; x.u = ((uint32_t)u) << 16;
    return x.f;
}
__device__ __forceinline__ float fast_sigmoid(float x) {
    x = fminf(fmaxf(x, -30.f), 30.f);
    return 1.f / (1.f + __expf(-x));
}
__device__ __forceinline__ float fast_tanh(float x) {
    x = fminf(fmaxf(x, -15.f), 15.f);
    float e = __expf(2.f * x);
    return (e - 1.f) / (e + 1.f);
}

__device__ __forceinline__ int ld_flag(int* p) {
    return __hip_atomic_load(p, __ATOMIC_RELAXED, __HIP_MEMORY_SCOPE_SYSTEM);
}
__device__ __forceinline__ void st_flag(int* p, int v) {
    __hip_atomic_store(p, v, __ATOMIC_RELAXED, __HIP_MEMORY_SCOPE_SYSTEM);
}

// Flag-array barrier: arrive = 1 store; wait = 64-lane parallel poll. No RMW.
// Poisoned flags are negative -> "< val" keeps waiting (poison-safe).
__device__ void flag_barrier(int* flags, int nf, int self, int val, bool fenced) {
    __syncthreads();                       // drains each wave's vmcnt (stores at MALL)
    if (threadIdx.x == 0) {
        if (fenced) __builtin_amdgcn_fence(__ATOMIC_RELEASE, "agent");
        st_flag(&flags[self * 16], val);
    }
    if (threadIdx.x < 64) {
        for (;;) {
            bool miss = false;
            for (int i = threadIdx.x; i < nf; i += 64)
                if (ld_flag(&flags[i * 16]) < val) miss = true;
            if (__ballot(miss) == 0ull) break;
            __builtin_amdgcn_s_sleep(2);
        }
    }
    if (fenced && threadIdx.x == 0)
        __builtin_amdgcn_fence(__ATOMIC_ACQUIRE, "agent");
    __syncthreads();
}

__device__ void wait_flag_ge(int* p, int target) {
    if (threadIdx.x == 0) {
        while (ld_flag(p) < target) __builtin_amdgcn_s_sleep(2);
    }
    __syncthreads();
}

__device__ __forceinline__ void cvt_chunk(const float* src, ushort* dst, int i) {
    float4 v = ((const float4*)src)[i];
    ushort4 o;
    o.x = f2b(v.x); o.y = f2b(v.y); o.z = f2b(v.z); o.w = f2b(v.w);
    ((ushort4*)dst)[i] = o;
}

// ---------------------------------------------------------------------------
// GEMM tile (device fn): C[m0:m0+64, n0:n0+128] = A @ W^T + bias.
// mode 0: GI  -> f32 write-through pair stores
// mode 1: UK  -> bf16 normal stores
// mode 2: WQ  -> bf16 write-through packed-pair stores
// ---------------------------------------------------------------------------
__device__ void gemm_tile(const ushort* __restrict__ A, const ushort* __restrict__ W,
                          const float* __restrict__ bias, float* Cf, ushort* C16,
                          int N, int K, int m0, int n0, int mode, ushort* SMEM) {
    ushort* As = SMEM;               // 64 x 72
    ushort* Bs = SMEM + 64 * 72;     // 128 x 72

    const int tid = threadIdx.x;
    const int w = tid >> 6, lane = tid & 63;
    const int lm = lane & 15, q = lane >> 4;
    const int wm = w >> 1, wn = w & 1;

    floatx4 acc[2][4];
#pragma unroll
    for (int i = 0; i < 2; ++i)
#pragma unroll
        for (int j = 0; j < 4; ++j)
            acc[i][j] = (floatx4){0.f, 0.f, 0.f, 0.f};

    short8 ar[2], br[4];
    auto load_tiles = [&](int k0) {
#pragma unroll
        for (int p = 0; p < 2; ++p) {
            int c = tid + p * 256;
            ar[p] = *(const short8*)&A[(size_t)(m0 + (c >> 3)) * K + k0 + (c & 7) * 8];
        }
#pragma unroll
        for (int p = 0; p < 4; ++p) {
            int c = tid + p * 256;
            br[p] = *(const short8*)&W[(size_t)(n0 + (c >> 3)) * K + k0 + (c & 7) * 8];
        }
    };

    load_tiles(0);
    for (int k0 = 0; k0 < K; k0 += 64) {
#pragma unroll
        for (int p = 0; p < 2; ++p) {
            int c = tid + p * 256;
            *(short8*)&As[(c >> 3) * 72 + (c & 7) * 8] = ar[p];
        }
#pragma unroll
        for (int p = 0; p < 4; ++p) {
            int c = tid + p * 256;
            *(short8*)&Bs[(c >> 3) * 72 + (c & 7) * 8] = br[p];
        }
        __syncthreads();
        if (k0 + 64 < K) load_tiles(k0 + 64);

#pragma unroll
        for (int kk = 0; kk < 2; ++kk) {
            short8 af[2], bf[4];
#pragma unroll
            for (int i = 0; i < 2; ++i)
                af[i] = *(const short8*)&As[(wm * 32 + i * 16 + lm) * 72 + kk * 32 + q * 8];
#pragma unroll
            for (int j = 0; j < 4; ++j)
                bf[j] = *(const short8*)&Bs[(wn * 64 + j * 16 + lm) * 72 + kk * 32 + q * 8];
#pragma unroll
            for (int i = 0; i < 2; ++i)
#pragma unroll
                for (int j = 0; j < 4; ++j)
                    acc[i][j] = __builtin_amdgcn_mfma_f32_16x16x32_bf16(af[i], bf[j], acc[i][j], 0, 0, 0);
        }
        __syncthreads();
    }

    float bv[4];
#pragma unroll
    for (int j = 0; j < 4; ++j)
        bv[j] = bias[n0 + wn * 64 + j * 16 + lm];
#pragma unroll
    for (int i = 0; i < 2; ++i) {
#pragma unroll
        for (int j = 0; j < 4; ++j) {
            int col = n0 + wn * 64 + j * 16 + lm;
#pragma unroll
            for (int r = 0; r < 4; ++r) {
                int row = m0 + wm * 32 + i * 16 + q * 4 + r;
                float v = acc[i][j][r] + bv[j];
                if (mode == 1) {
                    C16[(size_t)row * N + col] = f2b(v);
                } else if (mode == 0) {
                    float pv = __shfl(v, (lane + 1) & 63);
                    if ((lm & 1) == 0) {
                        union { float f[2]; unsigned long long u; } pk;
                        pk.f[0] = v; pk.f[1] = pv;
                        __hip_atomic_store((unsigned long long*)&Cf[(size_t)row * N + col],
                                           pk.u, __ATOMIC_RELAXED, __HIP_MEMORY_SCOPE_SYSTEM);
                    }
                } else {
                    int a16 = (int)f2b(v);
                    int pv = __shfl(a16, (lane + 1) & 63);
                    if ((lm & 1) == 0) {
                        uint packed = (uint)(a16 & 0xffff) | ((uint)pv << 16);
                        __hip_atomic_store((uint*)(C16 + (size_t)row * N + col), packed,
                                           __ATOMIC_RELAXED, __HIP_MEMORY_SCOPE_SYSTEM);
                    }
                }
            }
        }
    }
}

// ---------------------------------------------------------------------------
// Attention unit (device fn): one (t,b): scores+softmax+context+log_softmax
// ---------------------------------------------------------------------------
__device__ void attn_unit(int bt, const ushort* __restrict__ WQ16,
                          const ushort* __restrict__ UK16,
                          const float* __restrict__ va_w, const float* __restrict__ va_b,
                          const ushort* __restrict__ keysb, float* __restrict__ out,
                          ushort* SMEM) {
    float* wq_s = (float*)SMEM;          // 1024
    float* va_s = wq_s + 1024;           // 1024
    float* scb  = va_s + 1024;           // 64
    float* wred = scb + 64;              // 4
    float* sred = wred + 4;              // 4
    const int t = bt >> 6, b = bt & 63;
    const int tid = threadIdx.x;
    const int wave = tid >> 6, lane = tid & 63;

    for (int hh = tid; hh < H_DIM; hh += 256) {
        wq_s[hh] = b2f(WQ16[(size_t)(t * B_SZ + b) * H_DIM + hh]);
        va_s[hh] = va_w[hh];
    }
    __syncthreads();

    for (int s = wave; s < S_LEN; s += 4) {
        const ushort* uk = UK16 + ((size_t)b * S_LEN + s) * H_DIM + lane * 16;
        short8 u0 = *(const short8*)&uk[0];
        short8 u1 = *(const short8*)&uk[8];
        float acc = 0.f;
        const int h0 = lane * 16;
#pragma unroll
        for (int i = 0; i < 8; ++i)
            acc += fast_tanh(wq_s[h0 + i] + b2f((ushort)u0[i])) * va_s[h0 + i];
#pragma unroll
        for (int i = 0; i < 8; ++i)
            acc += fast_tanh(wq_s[h0 + 8 + i] + b2f((ushort)u1[i])) * va_s[h0 + 8 + i];
        for (int off = 32; off > 0; off >>= 1) acc += __shfl_down(acc, off);
        if (lane == 0) scb[s] = acc + va_b[0];
    }
    __syncthreads();

    if (tid < 64) {
        float v = (tid < S_LEN) ? scb[tid] : -INFINITY;
        float m = v;
        for (int off = 32; off > 0; off >>= 1) m = fmaxf(m, __shfl_down(m, off));
        m = __shfl(m, 0);
        float e = (tid < S_LEN) ? __expf(v - m) : 0.f;
        float sum = e;
        for (int off = 32; off > 0; off >>= 1) sum += __shfl_down(sum, off);
        sum = __shfl(sum, 0);
        if (tid < S_LEN) scb[tid] = e / sum;
    }
    __syncthreads();

    float c[8];
#pragma unroll
    for (int i = 0; i < 8; ++i) c[i] = 0.f;
    const ushort* kb = keysb + (size_t)b * S_LEN * D2H + tid * 8;
    for (int s = 0; s < S_LEN; ++s) {
        float ws = scb[s];
        short8 kv = *(const short8*)&kb[(size_t)s * D2H];
#pragma unroll
        for (int i = 0; i < 8; ++i) c[i] += ws * b2f((ushort)kv[i]);
    }

    float m = c[0];
#pragma unroll
    for (int i = 1; i < 8; ++i) m = fmaxf(m, c[i]);
    for (int off = 32; off > 0; off >>= 1) m = fmaxf(m, __shfl_down(m, off));
    if (lane == 0) wred[wave] = m;
    __syncthreads();
    if (tid == 0) wred[0] = fmaxf(fmaxf(wred[0], wred[1]), fmaxf(wred[2], wred[3]));
    __syncthreads();
    m = wred[0];
    float sum = 0.f;
#pragma unroll
    for (int i = 0; i < 8; ++i) sum += __expf(c[i] - m);
    for (int off = 32; off > 0; off >>= 1) sum += __shfl_down(sum, off);
    if (lane == 0) sred[wave] = sum;
    __syncthreads();
    if (tid == 0) sred[0] = sred[0] + sred[1] + sred[2] + sred[3];
    __syncthreads();
    float lse = m + __logf(sred[0]);

    float* o = out + ((size_t)b * T_LEN + t) * D2H + tid * 8;
#pragma unroll
    for (int i = 0; i < 8; ++i) o[i] = c[i] - lse;
    __syncthreads();
}

// ---------------------------------------------------------------------------
// The persistent mega-kernel. 256 blocks, 1/CU (LDS-bound), co-resident.
// flags layout (ints, x16 padding): gru@0[64] b1@1024[192] b2@4096[256]
//                                   b3@8192[256] giR@12288[10]
// ---------------------------------------------------------------------------
__global__ __launch_bounds__(256, 1) void mega(
    const float* __restrict__ enc_out, const float* __restrict__ hidden,
    const int* __restrict__ target, const float* __restrict__ emb,
    const float* __restrict__ w_ih, const float* __restrict__ w_hh,
    const float* __restrict__ b_ih, const float* __restrict__ b_hh,
    const float* __restrict__ wa_w, const float* __restrict__ wa_b,
    const float* __restrict__ ua_w, const float* __restrict__ ua_b,
    const float* __restrict__ va_w, const float* __restrict__ va_b,
    float* __restrict__ out,
    int* __restrict__ bar, float* __restrict__ GI,
    ushort* __restrict__ keysb, ushort* __restrict__ Xb,
    ushort* __restrict__ w_ihb, ushort* __restrict__ ua_wb,
    ushort* __restrict__ wa_wb, ushort* __restrict__ hb0,
    ushort* __restrict__ hsb, ushort* __restrict__ UK16,
    ushort* __restrict__ WQ16) {
    __shared__ ushort SMEM[48 * WS_STRIDE];   // 99 KB
    const int bid = blockIdx.x, tid = threadIdx.x;
    int* gruF = bar;
    int* b1F  = bar + 1024;
    int* b2F  = bar + 4096;
    int* b3F  = bar + 8192;
    int* giR  = bar + 12288;

    if (bid < NGRU) {
        // ---------------- GRU path ----------------
        const int w = tid >> 6, lane = tid & 63;
        const int lm = lane & 15, q = lane >> 4;
        const int j0 = bid * 16;
        const int j = j0 + lm;

        // stage own w_hh slice f32 -> bf16 -> LDS (no global w_hhb)
#pragma unroll
        for (int p = 0; p < 24; ++p) {
            int c = tid + p * 256;                // row=c>>7 (48), off=c&127 (x8 f32)
            int row = c >> 7, off = c & 127;
            int grow = (row >> 4) * H_DIM + j0 + (row & 15);
            const float* src = &w_hh[(size_t)grow * H_DIM + off * 8];
            float4 a = ((const float4*)src)[0];
            float4 bq = ((const float4*)src)[1];
            short8 s;
            s[0] = (short)f2b(a.x);  s[1] = (short)f2b(a.y);
            s[2] = (short)f2b(a.z);  s[3] = (short)f2b(a.w);
            s[4] = (short)f2b(bq.x); s[5] = (short)f2b(bq.y);
            s[6] = (short)f2b(bq.z); s[7] = (short)f2b(bq.w);
            *(short8*)&SMEM[row * WS_STRIDE + off * 8] = s;
        }

        // hb0: hidden f32 -> bf16 write-through (visible to all GRU blocks)
        {
            int i = bid * 256 + tid;              // 16384 float4 units
            float4 v = ((const float4*)hidden)[i];
            union { ushort4 s; unsigned long long u; } pk;
            pk.s.x = f2b(v.x); pk.s.y = f2b(v.y); pk.s.z = f2b(v.z); pk.s.w = f2b(v.w);
            __hip_atomic_store((unsigned long long*)hb0 + i, pk.u,
                               __ATOMIC_RELAXED, __HIP_MEMORY_SCOPE_SYSTEM);
        }

        const float bhr = b_hh[j], bhz = b_hh[H_DIM + j], bhn = b_hh[2 * H_DIM + j];
        float hf[4];
#pragma unroll
        for (int r = 0; r < 4; ++r)
            hf[r] = hidden[(size_t)(w * 16 + q * 4 + r) * H_DIM + j];

        // hb0-done barrier among the 64 GRU blocks (value 1)
        flag_barrier(gruF, NGRU, bid, 1, false);

        // wait GI tiles for t=0 (write-through data; normal loads safe)
        wait_flag_ge(&giR[0], 24);

        float ir[4], iz[4], inn[4];
#pragma unroll
        for (int r = 0; r < 4; ++r) {
            const float* gi = GI + (size_t)(w * 16 + q * 4 + r) * H3 + j;
            ir[r] = gi[0]; iz[r] = gi[H_DIM]; inn[r] = gi[2 * H_DIM];
        }

        float* outTail = out + (size_t)B_SZ * T_LEN * D2H;

        for (int t = 0; t < T_LEN; ++t) {
            const ushort* hin = (t == 0) ? hb0 : hsb + (size_t)(t - 1) * B_SZ * H_DIM;
            ushort* hout = hsb + (size_t)t * B_SZ * H_DIM;
            const ushort* arow = hin + (size_t)(w * 16 + lm) * H_DIM + q * 8;

            short8 hr[32];
            asm volatile(
                "global_load_dwordx4 %[h0], %[a], off sc0 sc1\n\t"
                "global_load_dwordx4 %[h1], %[a], off offset:64 sc0 sc1\n\t"
                "global_load_dwordx4 %[h2], %[a], off offset:128 sc0 sc1\n\t"
                "global_load_dwordx4 %[h3], %[a], off offset:192 sc0 sc1\n\t"
                "global_load_dwordx4 %[h4], %[a], off offset:256 sc0 sc1\n\t"
                "global_load_dwordx4 %[h5], %[a], off offset:320 sc0 sc1\n\t"
                "global_load_dwordx4 %[h6], %[a], off offset:384 sc0 sc1\n\t"
                "global_load_dwordx4 %[h7], %[a], off offset:448 sc0 sc1\n\t"
                "global_load_dwordx4 %[h8], %[a], off offset:512 sc0 sc1\n\t"
                "global_load_dwordx4 %[h9], %[a], off offset:576 sc0 sc1\n\t"
                "global_load_dwordx4 %[h10], %[a], off offset:640 sc0 sc1\n\t"
                "global_load_dwordx4 %[h11], %[a], off offset:704 sc0 sc1\n\t"
                "global_load_dwordx4 %[h12], %[a], off offset:768 sc0 sc1\n\t"
                "global_load_dwordx4 %[h13], %[a], off offset:832 sc0 sc1\n\t"
                "global_load_dwordx4 %[h14], %[a], off offset:896 sc0 sc1\n\t"
                "global_load_dwordx4 %[h15], %[a], off offset:960 sc0 sc1\n\t"
                "global_load_dwordx4 %[h16], %[a], off offset:1024 sc0 sc1\n\t"
                "global_load_dwordx4 %[h17], %[a], off offset:1088 sc0 sc1\n\t"
                "global_load_dwordx4 %[h18], %[a], off offset:1152 sc0 sc1\n\t"
                "global_load_dwordx4 %[h19], %[a], off offset:1216 sc0 sc1\n\t"
                "global_load_dwordx4 %[h20], %[a], off offset:1280 sc0 sc1\n\t"
                "global_load_dwordx4 %[h21], %[a], off offset:1344 sc0 sc1\n\t"
                "global_load_dwordx4 %[h22], %[a], off offset:1408 sc0 sc1\n\t"
                "global_load_dwordx4 %[h23], %[a], off offset:1472 sc0 sc1\n\t"
                "global_load_dwordx4 %[h24], %[a], off offset:1536 sc0 sc1\n\t"
                "global_load_dwordx4 %[h25], %[a], off offset:1600 sc0 sc1\n\t"
                "global_load_dwordx4 %[h26], %[a], off offset:1664 sc0 sc1\n\t"
                "global_load_dwordx4 %[h27], %[a], off offset:1728 sc0 sc1\n\t"
                "global_load_dwordx4 %[h28], %[a], off offset:1792 sc0 sc1\n\t"
                "global_load_dwordx4 %[h29], %[a], off offset:1856 sc0 sc1\n\t"
                "global_load_dwordx4 %[h30], %[a], off offset:1920 sc0 sc1\n\t"
                "global_load_dwordx4 %[h31], %[a], off offset:1984 sc0 sc1\n\t"
                "s_waitcnt vmcnt(0)"
                : [h0] "=&v"(hr[0]), [h1] "=&v"(hr[1]), [h2] "=&v"(hr[2]), [h3] "=&v"(hr[3]),
                  [h4] "=&v"(hr[4]), [h5] "=&v"(hr[5]), [h6] "=&v"(hr[6]), [h7] "=&v"(hr[7]),
                  [h8] "=&v"(hr[8]), [h9] "=&v"(hr[9]), [h10] "=&v"(hr[10]), [h11] "=&v"(hr[11]),
                  [h12] "=&v"(hr[12]), [h13] "=&v"(hr[13]), [h14] "=&v"(hr[14]), [h15] "=&v"(hr[15]),
                  [h16] "=&v"(hr[16]), [h17] "=&v"(hr[17]), [h18] "=&v"(hr[18]), [h19] "=&v"(hr[19]),
                  [h20] "=&v"(hr[20]), [h21] "=&v"(hr[21]), [h22] "=&v"(hr[22]), [h23] "=&v"(hr[23]),
                  [h24] "=&v"(hr[24]), [h25] "=&v"(hr[25]), [h26] "=&v"(hr[26]), [h27] "=&v"(hr[27]),
                  [h28] "=&v"(hr[28]), [h29] "=&v"(hr[29]), [h30] "=&v"(hr[30]), [h31] "=&v"(hr[31])
                : [a] "v"(arow)
                : "memory");

            floatx4 accr = {0.f, 0.f, 0.f, 0.f};
            floatx4 accz = {0.f, 0.f, 0.f, 0.f};
            floatx4 accn = {0.f, 0.f, 0.f, 0.f};

#pragma unroll
            for (int it = 0; it < 8; ++it) {
#pragma unroll
                for (int kk = 0; kk < 4; ++kk) {
                    const short8 af = hr[it * 4 + kk];
                    const int ko = it * 128 + kk * 32 + q * 8;
                    short8 b0 = *(const short8*)&SMEM[(lm) * WS_STRIDE + ko];
                    short8 b1 = *(const short8*)&SMEM[(16 + lm) * WS_STRIDE + ko];
                    short8 b2 = *(const short8*)&SMEM[(32 + lm) * WS_STRIDE + ko];
                    accr = __builtin_amdgcn_mfma_f32_16x16x32_bf16(af, b0, accr, 0, 0, 0);
                    accz = __builtin_amdgcn_mfma_f32_16x16x32_bf16(af, b1, accz, 0, 0, 0);
                    accn = __builtin_amdgcn_mfma_f32_16x16x32_bf16(af, b2, accn, 0, 0, 0);
                }
            }

            int h16v[4];
#pragma unroll
            for (int r = 0; r < 4; ++r) {
                float rg = fast_sigmoid(ir[r] + accr[r] + bhr);
                float z  = fast_sigmoid(iz[r] + accz[r] + bhz);
                float ng = fast_tanh(inn[r] + rg * (accn[r] + bhn));
                float hnew = (1.f - z) * ng + z * hf[r];
                hf[r] = hnew;
                h16v[r] = (int)f2b(hnew);
                if (t == T_LEN - 1) {
                    int b = w * 16 + q * 4 + r;
                    outTail[(size_t)b * H_DIM + j] = hnew;
                }
            }
#pragma unroll
            for (int r = 0; r < 4; ++r) {
                int pv = __shfl(h16v[r], (lane + 1) & 63);
                if ((lm & 1) == 0) {
                    int b = w * 16 + q * 4 + r;
                    uint packed = (uint)(h16v[r] & 0xffff) | ((uint)pv << 16);
                    __hip_atomic_store((uint*)hout + ((size_t)b * H_DIM + j) / 2, packed,
                                       __ATOMIC_RELAXED, __HIP_MEMORY_SCOPE_SYSTEM);
                }
            }

            if (t < T_LEN - 1) {
                wait_flag_ge(&giR[(t + 1) * 16], 24);   // usually instant
#pragma unroll
                for (int r = 0; r < 4; ++r) {
                    const float* gi = GI + (size_t)((t + 1) * B_SZ + w * 16 + q * 4 + r) * H3 + j;
                    ir[r] = gi[0]; iz[r] = gi[H_DIM]; inn[r] = gi[2 * H_DIM];
                }
                flag_barrier(gruF, NGRU, bid, t + 2, false);
            }
        }
    } else {
        // ---------------- GEMM path ----------------
        const int g = bid - NGRU;                 // 0..191
        if (g == 0 && tid < 10) st_flag(&giR[tid * 16], 0);

        // P0: conversions + gathers (8448 units / 192 blocks = 44 each)
        for (int u = g * 44; u < g * 44 + 44; ++u) {
            if (u < 1536) {
                cvt_chunk(w_ih, w_ihb, u * 256 + tid);
            } else if (u < 3584) {
                cvt_chunk(ua_w, ua_wb, (u - 1536) * 256 + tid);
            } else if (u < 4608) {
                cvt_chunk(wa_w, wa_wb, (u - 3584) * 256 + tid);
            } else if (u < 7808) {
                int bs = u - 4608;                // b*S + s
                int b = bs / S_LEN, s = bs % S_LEN;
                const float* src = enc_out + ((size_t)s * B_SZ + b) * D2H;
                ushort* dst = keysb + (size_t)bs * D2H;
#pragma unroll
                for (int p = 0; p < 2; ++p) {
                    int i = tid + p * 256;
                    float4 v = ((const float4*)src)[i];
                    ushort4 o;
                    o.x = f2b(v.x); o.y = f2b(v.y); o.z = f2b(v.z); o.w = f2b(v.w);
                    ((ushort4*)dst)[i] = o;
                }
            } else {
                int m = u - 7808;                 // t*B + b
                int t = m / B_SZ, b = m % B_SZ;
                int idx = (t == 0) ? 0 : target[b * T_LEN + (t - 1)];
                if (tid < 128) {
                    const float* src = emb + (size_t)idx * E_DIM;
                    float4 v = ((const float4*)src)[tid];
                    ushort4 o;
                    o.x = f2b(v.x); o.y = f2b(v.y); o.z = f2b(v.z); o.w = f2b(v.w);
                    ((ushort4*)(Xb + (size_t)m * E_DIM))[tid] = o;
                }
            }
        }

        // B1 (fenced) among the 192 GEMM blocks
        flag_barrier(b1F, NGEMM, g, 1, true);

        // P1: GI tiles (0..239, t-ordered) then UK tiles (240..639)
        for (int tile = g; tile < 640; tile += NGEMM) {
            if (tile < 240) {
                int t = tile / 24, nn = tile % 24;
                gemm_tile(Xb, w_ihb, b_ih, GI, nullptr, H3, E_DIM,
                          t * 64, nn * 128, 0, SMEM);
                __syncthreads();                  // drain all waves' WT stores
                if (tid == 0)
                    __hip_atomic_fetch_add(&giR[t * 16], 1,
                                           __ATOMIC_RELAXED, __HIP_MEMORY_SCOPE_SYSTEM);
            } else {
                int u = tile - 240;
                gemm_tile(keysb, ua_wb, ua_b, nullptr, UK16, H_DIM, D2H,
                          (u / 8) * 64, (u % 8) * 128, 1, SMEM);
            }
        }
    }

    // B2 (fenced) over all 256 blocks
    flag_barrier(b2F, NBLK, bid, 1, true);

    // P2: WQ tiles (80) -> flag barrier -> attention (640 units)
    if (bid < 80) {
        gemm_tile(hsb, wa_wb, wa_b, nullptr, WQ16, H_DIM, H_DIM,
                  (bid / 8) * 64, (bid % 8) * 128, 2, SMEM);
    }
    flag_barrier(b3F, NBLK, bid, 1, false);

    for (int u = bid; u < 640; u += NBLK)
        attn_unit(u, WQ16, UK16, va_w, va_b, keysb, out, SMEM);
}

// ---------------------------------------------------------------------------
extern "C" void kernel_launch(void* const* d_in, const int* in_sizes, int n_in,
                              void* d_out, int out_size, void* d_ws, size_t ws_size,
                              hipStream_t stream) {
    const float* enc_out = (const float*)d_in[0];
    const float* hidden  = (const float*)d_in[1];
    const int*   target  = (const int*)d_in[2];
    const float* emb     = (const float*)d_in[3];
    const float* w_ih    = (const float*)d_in[4];
    const float* w_hh    = (const float*)d_in[5];
    const float* b_ih    = (const float*)d_in[6];
    const float* b_hh    = (const float*)d_in[7];
    const float* wa_w    = (const float*)d_in[8];
    const float* wa_b    = (const float*)d_in[9];
    const float* ua_w    = (const float*)d_in[10];
    const float* ua_b    = (const float*)d_in[11];
    const float* va_w    = (const float*)d_in[12];
    const float* va_b    = (const float*)d_in[13];
    float* out = (float*)d_out;

    const int TB = T_LEN * B_SZ;               // 640
    const int BS = B_SZ * S_LEN;               // 3200

    // workspace carve (16B-aligned chunks)
    char* p = (char*)d_ws;
    int*    bar   = (int*)p;    p += 16384 * 4;                    // 64 KB flags
    float*  GI    = (float*)p;  p += (size_t)TB * H3 * 4;
    p = (char*)(((uintptr_t)p + 255) & ~(uintptr_t)255);
    ushort* keysb = (ushort*)p; p += (size_t)BS * D2H * 2;
    ushort* Xb    = (ushort*)p; p += (size_t)TB * E_DIM * 2;
    ushort* w_ihb = (ushort*)p; p += (size_t)H3 * E_DIM * 2;
    ushort* ua_wb = (ushort*)p; p += (size_t)H_DIM * D2H * 2;
    ushort* wa_wb = (ushort*)p; p += (size_t)H_DIM * H_DIM * 2;
    ushort* hb0   = (ushort*)p; p += (size_t)B_SZ * H_DIM * 2;
    ushort* hsb   = (ushort*)p; p += (size_t)TB * H_DIM * 2;
    ushort* UK16  = (ushort*)p; p += (size_t)BS * H_DIM * 2;
    ushort* WQ16  = (ushort*)p; p += (size_t)TB * H_DIM * 2;

    mega<<<NBLK, 256, 0, stream>>>(enc_out, hidden, target, emb, w_ih, w_hh,
                                   b_ih, b_hh, wa_w, wa_b, ua_w, ua_b, va_w, va_b,
                                   out, bar, GI, keysb, Xb, w_ihb, ua_wb, wa_wb,
                                   hb0, hsb, UK16, WQ16);
}